// Round 6
// baseline (649.807 us; speedup 1.0000x reference)
//
#include <hip/hip_runtime.h>
#include <math.h>

#define NB 16
#define PP 2500
#define WWD 50
#define NANCH 22500
#define CIN 512
#define PRE 6000
#define POST 300
#define NW64 94          // ceil(6000/64): 94*64 = 6016 bits
#define NW32 188
#define SEG 2816         // per-segment rows (8 segs: 8*2816 = 22528 >= 22500)
#define SEGP 4096        // padded power-of-2
#define RUN 6016         // truncated run length after merges (rank-safe > 6000)
#define KT 8             // gemm K-tile

// d_out float offsets (elements)
#define OFF_LOCS   0
#define OFF_SCORES 1440000
#define OFF_ROIS   2160000
#define OFF_ROIIX  2179200
#define OFF_ANCH   2184000

typedef unsigned long long u64;
typedef unsigned u32;

// ---- anchor for row r: f32-faithful to _enumerate_anchors (f64 base -> f32, f32 add) ----
__device__ inline float4 anchor_of(int r) {
    int p = r / 9, a = r - p * 9;
    int gy = p / WWD, gx = p - gy * WWD;
    int ri = a / 3, si = a - ri * 3;
    double ratio = (ri == 0) ? 0.5 : (ri == 1 ? 1.0 : 2.0);
    double scale = (si == 0) ? 8.0 : (si == 1 ? 16.0 : 32.0);
    double hh = 16.0 * scale * sqrt(ratio);
    double wd = 16.0 * scale * sqrt(1.0 / ratio);
    float by1 = (float)(8.0 - hh * 0.5);
    float bx1 = (float)(8.0 - wd * 0.5);
    float by2 = (float)(8.0 + hh * 0.5);
    float bx2 = (float)(8.0 + wd * 0.5);
    float sy = (float)gy * 16.0f, sx = (float)gx * 16.0f;
    return make_float4(sy + by1, sx + bx1, sy + by2, sx + bx2);
}

// ---- decode + clip + min-size: f32-faithful to _loc2bbox/_propose_one ----
__device__ inline float4 decode_box(const float* __restrict__ lp, float4 an,
                                    float ih, float iw, bool* ok) {
    float dy = lp[0], dx = lp[1], dh = lp[2], dw = lp[3];
    float h = an.z - an.x, w = an.w - an.y;
    float cy = an.x + 0.5f * h, cx = an.y + 0.5f * w;
    float ny = dy * h + cy, nx = dx * w + cx;
    float nh = expf(dh) * h, nw = expf(dw) * w;
    float y1 = fminf(fmaxf(ny - 0.5f * nh, 0.f), ih);
    float x1 = fminf(fmaxf(nx - 0.5f * nw, 0.f), iw);
    float y2 = fminf(fmaxf(ny + 0.5f * nh, 0.f), ih);
    float x2 = fminf(fmaxf(nx + 0.5f * nw, 0.f), iw);
    *ok = ((y2 - y1) >= 16.0f) && ((x2 - x1) >= 16.0f);
    return make_float4(y1, x1, y2, x2);
}

__device__ inline float iou_f32(float4 a, float4 b) {
    float ty1 = fmaxf(a.x, b.x), tx1 = fmaxf(a.y, b.y);
    float ty2 = fminf(a.z, b.z), tx2 = fminf(a.w, b.w);
    float inter = fmaxf(ty2 - ty1, 0.f) * fmaxf(tx2 - tx1, 0.f);
    float aa = (a.z - a.x) * (a.w - a.y);
    float ab = (b.z - b.x) * (b.w - b.y);
    return inter / fmaxf(aa + ab - inter, 1e-9f);
}

// ---------------- Kernel 1: relu + dual 1x1 conv ----------------
// 1-wave blocks, __launch_bounds__(64,1) -> VGPR cap 512: acc[54] + double-
// buffered x tiles stay in registers (round-5 spilled at the default cap=72).
// Weights read via wave-uniform indices -> s_load into SGPRs (proven r5: SGPR=112).
// Accumulation order (single chain, ascending c per output) bit-identical to
// the passing rounds.
__global__ __launch_bounds__(64, 1) void k_gemm(
    const float* __restrict__ x, const float* __restrict__ lw, const float* __restrict__ lb,
    const float* __restrict__ sw, const float* __restrict__ sb, float* __restrict__ out)
{
    int b  = blockIdx.x / 40;
    int pt = blockIdx.x % 40;
    int p  = pt * 64 + threadIdx.x;
    bool act = (p < PP);
    int pc = act ? p : (PP - 1);
    const float* xb = x + (size_t)b * (CIN * PP) + pc;

    float acc[54];
#pragma unroll
    for (int o = 0; o < 54; ++o) acc[o] = 0.f;

    float xvA[KT], xvB[KT];
#pragma unroll
    for (int cc = 0; cc < KT; ++cc) xvA[cc] = fmaxf(xb[(size_t)cc * PP], 0.f);

#pragma unroll 1
    for (int t = 0; t < CIN / KT; t += 2) {
        int c0 = t * KT;
        // prefetch tile t+1
#pragma unroll
        for (int cc = 0; cc < KT; ++cc)
            xvB[cc] = fmaxf(xb[(size_t)(c0 + KT + cc) * PP], 0.f);
        // FMA tile t (weights via uniform scalar loads)
#pragma unroll
        for (int o = 0; o < 36; ++o) {
            const float* wr = lw + (size_t)o * CIN + c0;
#pragma unroll
            for (int cc = 0; cc < KT; ++cc) acc[o] += xvA[cc] * wr[cc];
        }
#pragma unroll
        for (int o = 0; o < 18; ++o) {
            const float* wr = sw + (size_t)o * CIN + c0;
#pragma unroll
            for (int cc = 0; cc < KT; ++cc) acc[36 + o] += xvA[cc] * wr[cc];
        }
        // prefetch tile t+2
        if (t + 2 < CIN / KT) {
#pragma unroll
            for (int cc = 0; cc < KT; ++cc)
                xvA[cc] = fmaxf(xb[(size_t)(c0 + 2 * KT + cc) * PP], 0.f);
        }
        // FMA tile t+1
#pragma unroll
        for (int o = 0; o < 36; ++o) {
            const float* wr = lw + (size_t)o * CIN + c0 + KT;
#pragma unroll
            for (int cc = 0; cc < KT; ++cc) acc[o] += xvB[cc] * wr[cc];
        }
#pragma unroll
        for (int o = 0; o < 18; ++o) {
            const float* wr = sw + (size_t)o * CIN + c0 + KT;
#pragma unroll
            for (int cc = 0; cc < KT; ++cc) acc[36 + o] += xvB[cc] * wr[cc];
        }
    }

    if (!act) return;
    float* lo = out + OFF_LOCS + ((size_t)b * PP + p) * 36;   // 144B stride, 16B-aligned
#pragma unroll
    for (int q = 0; q < 9; ++q) {
        float4 v = make_float4(acc[4 * q] + lb[4 * q],
                               acc[4 * q + 1] + lb[4 * q + 1],
                               acc[4 * q + 2] + lb[4 * q + 2],
                               acc[4 * q + 3] + lb[4 * q + 3]);
        ((float4*)lo)[q] = v;
    }
    float* so = out + OFF_SCORES + ((size_t)b * PP + p) * 18; // 72B stride, 8B-aligned
#pragma unroll
    for (int q = 0; q < 9; ++q) {
        float2 v = make_float2(acc[36 + 2 * q] + sb[2 * q],
                               acc[36 + 2 * q + 1] + sb[2 * q + 1]);
        ((float2*)so)[q] = v;
    }
}

// ---------------- Kernel 2: per-segment key-gen + bitonic sort (desc) ----------------
__global__ __launch_bounds__(1024) void k_sort1(
    const float* __restrict__ out_ro, float* __restrict__ out, u64* __restrict__ runs,
    const int* __restrict__ imh_p, const int* __restrict__ imw_p)
{
    __shared__ u64 sk[SEGP];         // 32 KB
    int blk = blockIdx.x;
    int b = blk >> 3, s = blk & 7;
    int tid = threadIdx.x;
    int base = s * SEG;
    float ih = (float)imh_p[0], iw = (float)imw_p[0];

    for (int i = tid; i < SEGP; i += 1024) {
        int r = base + i;
        u64 key = 0ull;
        if (i < SEG && r < NANCH) {
            float4 an = anchor_of(r);
            if (b == 0) ((float4*)(out + OFF_ANCH))[r] = an;
            bool ok;
            (void)decode_box(out_ro + (size_t)OFF_LOCS + ((size_t)b * NANCH + r) * 4,
                             an, ih, iw, &ok);
            int p = r / 9, a = r - p * 9;
            const float* sp = out_ro + (size_t)OFF_SCORES + ((size_t)b * PP + p) * 18 + a * 2;
            float s0 = sp[0], s1 = sp[1];
            float mx = fmaxf(s0, s1);
            float e0 = expf(s0 - mx), e1 = expf(s1 - mx);
            float fg = e1 / (e0 + e1);
            float sc = ok ? fg : -INFINITY;
            u32 sb = __float_as_uint(sc);
            sb = (sb & 0x80000000u) ? ~sb : (sb | 0x80000000u);
            key = ((u64)sb << 32) | (u64)(u32)(NANCH - r);   // unique; idx-asc tiebreak
        }
        sk[i] = key;
    }
    __syncthreads();
    for (int kk = 2; kk <= SEGP; kk <<= 1) {
        for (int j = kk >> 1; j > 0; j >>= 1) {
            for (int i = tid; i < SEGP; i += 1024) {
                int ij = i ^ j;
                if (ij > i) {
                    u64 va = sk[i], vb = sk[ij];
                    bool up = ((i & kk) == 0);
                    if (up ? (va < vb) : (va > vb)) { sk[i] = vb; sk[ij] = va; }
                }
            }
            __syncthreads();
        }
    }
    u64* dst = runs + (size_t)blk * SEGP;
    for (int i = tid; i < SEGP; i += 1024) dst[i] = sk[i];
}

// ---------------- merge-path pairwise merge (descending, unique keys) ----------------
__device__ inline int mp_search(const u64* __restrict__ A, const u64* __restrict__ B,
                                int LA, int LB, int d) {
    int lo = max(0, d - LB), hi = min(d, LA);
    while (lo < hi) {
        int mid = (lo + hi) >> 1;
        if (A[mid] > B[d - 1 - mid]) lo = mid + 1; else hi = mid;
    }
    return lo;
}

__global__ __launch_bounds__(1024) void k_merge(
    const u64* __restrict__ in, u64* __restrict__ outk,
    int runLen, int pairsPerBatch, int outLen)
{
    int blk = blockIdx.x;
    int b = blk / pairsPerBatch, m = blk - b * pairsPerBatch;
    const u64* A = in + ((size_t)b * pairsPerBatch * 2 + 2 * m) * runLen;
    const u64* B = A + runLen;
    u64* C = outk + ((size_t)b * pairsPerBatch + m) * outLen;
    int E = (outLen + 1023) >> 10;
    int d0 = threadIdx.x * E;
    if (d0 >= outLen) return;
    int cnt = min(E, outLen - d0);
    int i = mp_search(A, B, runLen, runLen, d0);
    int j = d0 - i;
    for (int e = 0; e < cnt; ++e) {
        u64 va = (i < runLen) ? A[i] : 0ull;
        u64 vb = (j < runLen) ? B[j] : 0ull;
        bool takeA = (j >= runLen) || ((i < runLen) && (va > vb));
        C[d0 + e] = takeA ? va : vb;
        if (takeA) ++i; else ++j;
    }
}

// ---------------- final merge + emit boxes (top-6000, sorted) ----------------
__global__ __launch_bounds__(1024) void k_merge_emit(
    const u64* __restrict__ in, const float* __restrict__ out_ro,
    float* __restrict__ topBoxes, u32* __restrict__ topValid,
    const int* __restrict__ imh_p, const int* __restrict__ imw_p)
{
    int b = blockIdx.x;
    const u64* A = in + (size_t)b * 2 * RUN;
    const u64* B = A + RUN;
    float ih = (float)imh_p[0], iw = (float)imw_p[0];
    int E = (PRE + 1023) >> 10;   // 6
    int d0 = threadIdx.x * E;
    if (d0 >= PRE) return;
    int cnt = min(E, PRE - d0);
    int i = mp_search(A, B, RUN, RUN, d0);
    int j = d0 - i;
    for (int e = 0; e < cnt; ++e) {
        u64 va = (i < RUN) ? A[i] : 0ull;
        u64 vb = (j < RUN) ? B[j] : 0ull;
        bool takeA = (j >= RUN) || ((i < RUN) && (va > vb));
        u64 key = takeA ? va : vb;
        if (takeA) ++i; else ++j;
        int d = d0 + e;
        bool valid = (key >> 63) != 0ull;
        int idx = valid ? (NANCH - (int)(key & 0xFFFFFFFFull)) : 0;
        bool ok;
        float4 an = anchor_of(idx);
        float4 bx = decode_box(out_ro + (size_t)OFF_LOCS + ((size_t)b * NANCH + idx) * 4,
                               an, ih, iw, &ok);
        ((float4*)topBoxes)[(size_t)b * PRE + d] = bx;
        topValid[(size_t)b * PRE + d] = valid ? 1u : 0u;
    }
}

// ---------------- Kernel 4: lazy/JIT greedy NMS, early stop at 300 kept ----------------
__global__ __launch_bounds__(1024) void k_nms(const float* __restrict__ topBoxes,
                                              const u32* __restrict__ topValid,
                                              float* __restrict__ out)
{
    __shared__ float4 chunkB[64];
    __shared__ float4 keptB[POST];
    __shared__ u32 sup[NW32];
    __shared__ int s_nk;
    __shared__ int s_stop;
    int b = blockIdx.x, tid = threadIdx.x;
    int wave = tid >> 6, lane = tid & 63;
    const float4* tb = (const float4*)topBoxes + (size_t)b * PRE;

    for (int i = tid; i < NW32; i += 1024) sup[i] = 0u;
    if (tid == 0) { s_nk = 0; s_stop = 0; }
    __syncthreads();
    for (int r = tid; r < PRE; r += 1024)
        if (!topValid[(size_t)b * PRE + r]) atomicOr(&sup[r >> 5], 1u << (r & 31));
    if (tid == 0) atomicOr(&sup[187], 0xFFFF0000u);   // bits 6000..6015 invalid
    __syncthreads();

    for (int c = 0; c < NW64; ++c) {
        int base = c * 64;
        if (tid < 64)
            chunkB[tid] = (base + tid < PRE) ? tb[base + tid]
                                             : make_float4(0.f, 0.f, 0.f, 0.f);
        // ---- JIT: suppress this chunk's rows vs kept list so far ----
        int nk0 = s_nk;
        bool s = false;
        if (nk0 > 0 && base + lane < PRE) {
            float4 bj = tb[base + lane];
            for (int t = wave; t < nk0; t += 16)
                s |= iou_f32(keptB[t], bj) > 0.7f;
        }
        u64 bal = __ballot(s);
        if (lane == 0 && bal) {
            atomicOr(&sup[2 * c], (u32)bal);
            atomicOr(&sup[2 * c + 1], (u32)(bal >> 32));
        }
        __syncthreads();
        // ---- phase A: wave 0 resolves chunk serially ----
        if (wave == 0) {
            u64 avail = ~(((u64)sup[2 * c + 1] << 32) | (u64)sup[2 * c]);
            float4 myB = chunkB[lane];
            int nkl = s_nk;
            while (avail && nkl < POST) {
                int i = __builtin_ctzll(avail);
                float4 bi = chunkB[i];
                if (lane == 0) keptB[nkl] = bi;
                nkl++;
                bool ss = iou_f32(bi, myB) > 0.7f;
                u64 bb = __ballot(ss);
                avail &= ~((1ull << i) | bb);
            }
            if (lane == 0) { s_nk = nkl; if (nkl >= POST) s_stop = 1; }
        }
        __syncthreads();
        if (s_stop) break;
    }

    __syncthreads();
    int nk = min(s_nk, POST);
    for (int r = tid; r < POST; r += 1024) {
        float4 v = make_float4(0.f, 0.f, 0.f, 0.f);
        if (r < nk) v = keptB[r];
        ((float4*)(out + OFF_ROIS))[(size_t)b * POST + r] = v;
        out[(size_t)OFF_ROIIX + (size_t)b * POST + r] = (float)b;
    }
}

// ---------------- launch ----------------
extern "C" void kernel_launch(void* const* d_in, const int* in_sizes, int n_in,
                              void* d_out, int out_size, void* d_ws, size_t ws_size,
                              hipStream_t stream) {
    const float* x  = (const float*)d_in[0];
    const int* imh  = (const int*)d_in[1];
    const int* imw  = (const int*)d_in[2];
    // d_in[3]=conv1_w, d_in[4]=conv1_b: unused by the reference
    const float* sw = (const float*)d_in[5];
    const float* sb = (const float*)d_in[6];
    const float* lw = (const float*)d_in[7];
    const float* lb = (const float*)d_in[8];
    float* out = (float*)d_out;
    char* wsb = (char*)d_ws;

    u64*   runs0    = (u64*)(wsb);                     // 16*8*4096*8  = 4,194,304 B
    u64*   runs1    = (u64*)(wsb + 4194304);           // 16*4*6016*8  = 3,080,192 B
    u64*   runs2    = (u64*)(wsb + 7274496);           // 16*2*6016*8  = 1,540,096 B
    float* topBoxes = (float*)(wsb + 8814592);         // 16*6000*16   = 1,536,000 B
    u32*   topValid = (u32*)(wsb + 10350592);          // 16*6000*4    =   384,000 B

    hipLaunchKernelGGL(k_gemm, dim3(NB * 40), dim3(64), 0, stream,
                       x, lw, lb, sw, sb, out);
    hipLaunchKernelGGL(k_sort1, dim3(NB * 8), dim3(1024), 0, stream,
                       out, out, runs0, imh, imw);
    hipLaunchKernelGGL(k_merge, dim3(NB * 4), dim3(1024), 0, stream,
                       runs0, runs1, SEGP, 4, RUN);
    hipLaunchKernelGGL(k_merge, dim3(NB * 2), dim3(1024), 0, stream,
                       runs1, runs2, RUN, 2, RUN);
    hipLaunchKernelGGL(k_merge_emit, dim3(NB), dim3(1024), 0, stream,
                       runs2, out, topBoxes, topValid, imh, imw);
    hipLaunchKernelGGL(k_nms, dim3(NB), dim3(1024), 0, stream,
                       topBoxes, topValid, out);
}

// Round 7
// 333.769 us; speedup vs baseline: 1.9469x; 1.9469x over previous
//
#include <hip/hip_runtime.h>
#include <math.h>

#define NB 16
#define PP 2500
#define WWD 50
#define NANCH 22500
#define CIN 512
#define PRE 6000
#define POST 300
#define NW64 94          // ceil(6000/64): 94*64 = 6016 bits
#define NW32 188
#define SEG 2816         // per-segment rows (8 segs: 8*2816 = 22528 >= 22500)
#define SEGP 4096        // padded power-of-2
#define RUN 6016         // truncated run length after merges (rank-safe > 6000)
#define KT 16            // gemm K-tile

// d_out float offsets (elements)
#define OFF_LOCS   0
#define OFF_SCORES 1440000
#define OFF_ROIS   2160000
#define OFF_ROIIX  2179200
#define OFF_ANCH   2184000

typedef unsigned long long u64;
typedef unsigned u32;

// ---- anchor for row r: f32-faithful to _enumerate_anchors (f64 base -> f32, f32 add) ----
__device__ inline float4 anchor_of(int r) {
    int p = r / 9, a = r - p * 9;
    int gy = p / WWD, gx = p - gy * WWD;
    int ri = a / 3, si = a - ri * 3;
    double ratio = (ri == 0) ? 0.5 : (ri == 1 ? 1.0 : 2.0);
    double scale = (si == 0) ? 8.0 : (si == 1 ? 16.0 : 32.0);
    double hh = 16.0 * scale * sqrt(ratio);
    double wd = 16.0 * scale * sqrt(1.0 / ratio);
    float by1 = (float)(8.0 - hh * 0.5);
    float bx1 = (float)(8.0 - wd * 0.5);
    float by2 = (float)(8.0 + hh * 0.5);
    float bx2 = (float)(8.0 + wd * 0.5);
    float sy = (float)gy * 16.0f, sx = (float)gx * 16.0f;
    return make_float4(sy + by1, sx + bx1, sy + by2, sx + bx2);
}

// ---- decode + clip + min-size: f32-faithful to _loc2bbox/_propose_one ----
__device__ inline float4 decode_box(const float* __restrict__ lp, float4 an,
                                    float ih, float iw, bool* ok) {
    float dy = lp[0], dx = lp[1], dh = lp[2], dw = lp[3];
    float h = an.z - an.x, w = an.w - an.y;
    float cy = an.x + 0.5f * h, cx = an.y + 0.5f * w;
    float ny = dy * h + cy, nx = dx * w + cx;
    float nh = expf(dh) * h, nw = expf(dw) * w;
    float y1 = fminf(fmaxf(ny - 0.5f * nh, 0.f), ih);
    float x1 = fminf(fmaxf(nx - 0.5f * nw, 0.f), iw);
    float y2 = fminf(fmaxf(ny + 0.5f * nh, 0.f), ih);
    float x2 = fminf(fmaxf(nx + 0.5f * nw, 0.f), iw);
    *ok = ((y2 - y1) >= 16.0f) && ((x2 - x1) >= 16.0f);
    return make_float4(y1, x1, y2, x2);
}

__device__ inline float iou_f32(float4 a, float4 b) {
    float ty1 = fmaxf(a.x, b.x), tx1 = fmaxf(a.y, b.y);
    float ty2 = fminf(a.z, b.z), tx2 = fminf(a.w, b.w);
    float inter = fmaxf(ty2 - ty1, 0.f) * fmaxf(tx2 - tx1, 0.f);
    float aa = (a.z - a.x) * (a.w - a.y);
    float ab = (b.z - b.x) * (b.w - b.y);
    return inter / fmaxf(aa + ab - inter, 1e-9f);
}

// ---------------- Kernel 1: relu + dual 1x1 conv ----------------
// 1 wave = 64 positions x 14 outputs (output-group og from blockIdx -> SGPR-
// uniform -> weight rows via s_load, proven r5/r6). acc[14]+xv[32] ~ 60 VGPR
// < 128 cap from __launch_bounds__(64,4): no spill (r5/r6 failure mode).
// 2560 waves = 2.5/SIMD. Per-output accumulation: single chain ascending c,
// bias last — bit-identical to all passing rounds.
__global__ __launch_bounds__(64, 4) void k_gemm(
    const float* __restrict__ x, const float* __restrict__ lw, const float* __restrict__ lb,
    const float* __restrict__ sw, const float* __restrict__ sb, float* __restrict__ out)
{
    int bid = blockIdx.x;
    int b   = bid / 160;           // batch
    int rem = bid - b * 160;
    int pt  = rem >> 2;            // position tile 0..39
    int og  = rem & 3;             // output group 0..3 (SGPR-uniform)
    int p   = pt * 64 + threadIdx.x;
    bool act = (p < PP);
    int pc = act ? p : (PP - 1);
    const float* xb = x + (size_t)b * (CIN * PP) + pc;

    int o0  = og * 14;
    int cnt = (og == 3) ? 12 : 14;

    // per-k weight-row pointers + biases (uniform -> SGPR after SROA)
    const float* rowp[14];
    float bias[14];
#pragma unroll
    for (int k = 0; k < 14; ++k) {
        int o = o0 + k;
        int oc = (o < 54) ? o : 53;              // og=3 tail clamp (never stored)
        rowp[k] = (oc < 36) ? (lw + (size_t)oc * CIN) : (sw + (size_t)(oc - 36) * CIN);
        bias[k] = (oc < 36) ? lb[oc] : sb[oc - 36];
    }

    float acc[14];
#pragma unroll
    for (int k = 0; k < 14; ++k) acc[k] = 0.f;

    float xvA[KT], xvB[KT];
#pragma unroll
    for (int cc = 0; cc < KT; ++cc) xvA[cc] = fmaxf(xb[(size_t)cc * PP], 0.f);

#pragma unroll 1
    for (int t = 0; t < CIN / KT; t += 2) {
        int c0 = t * KT;
        // prefetch tile t+1
#pragma unroll
        for (int cc = 0; cc < KT; ++cc)
            xvB[cc] = fmaxf(xb[(size_t)(c0 + KT + cc) * PP], 0.f);
        // FMA tile t (weights via scalar loads)
#pragma unroll
        for (int k = 0; k < 14; ++k) {
            const float* wr = rowp[k] + c0;
#pragma unroll
            for (int cc = 0; cc < KT; ++cc) acc[k] += xvA[cc] * wr[cc];
        }
        // prefetch tile t+2
        if (t + 2 < CIN / KT) {
#pragma unroll
            for (int cc = 0; cc < KT; ++cc)
                xvA[cc] = fmaxf(xb[(size_t)(c0 + 2 * KT + cc) * PP], 0.f);
        }
        // FMA tile t+1
#pragma unroll
        for (int k = 0; k < 14; ++k) {
            const float* wr = rowp[k] + c0 + KT;
#pragma unroll
            for (int cc = 0; cc < KT; ++cc) acc[k] += xvB[cc] * wr[cc];
        }
    }

    if (!act) return;
#pragma unroll
    for (int k = 0; k < 14; ++k) {
        if (k < cnt) {
            int o = o0 + k;
            if (o < 36)
                out[(size_t)OFF_LOCS + ((size_t)b * PP + p) * 36 + o] = acc[k] + bias[k];
            else
                out[(size_t)OFF_SCORES + ((size_t)b * PP + p) * 18 + (o - 36)] = acc[k] + bias[k];
        }
    }
}

// ---------------- Kernel 2: per-segment key-gen + bitonic sort (desc) ----------------
__global__ __launch_bounds__(1024) void k_sort1(
    const float* __restrict__ out_ro, float* __restrict__ out, u64* __restrict__ runs,
    const int* __restrict__ imh_p, const int* __restrict__ imw_p)
{
    __shared__ u64 sk[SEGP];         // 32 KB
    int blk = blockIdx.x;
    int b = blk >> 3, s = blk & 7;
    int tid = threadIdx.x;
    int base = s * SEG;
    float ih = (float)imh_p[0], iw = (float)imw_p[0];

    for (int i = tid; i < SEGP; i += 1024) {
        int r = base + i;
        u64 key = 0ull;
        if (i < SEG && r < NANCH) {
            float4 an = anchor_of(r);
            if (b == 0) ((float4*)(out + OFF_ANCH))[r] = an;
            bool ok;
            (void)decode_box(out_ro + (size_t)OFF_LOCS + ((size_t)b * NANCH + r) * 4,
                             an, ih, iw, &ok);
            int p = r / 9, a = r - p * 9;
            const float* sp = out_ro + (size_t)OFF_SCORES + ((size_t)b * PP + p) * 18 + a * 2;
            float s0 = sp[0], s1 = sp[1];
            float mx = fmaxf(s0, s1);
            float e0 = expf(s0 - mx), e1 = expf(s1 - mx);
            float fg = e1 / (e0 + e1);
            float sc = ok ? fg : -INFINITY;
            u32 sb = __float_as_uint(sc);
            sb = (sb & 0x80000000u) ? ~sb : (sb | 0x80000000u);
            key = ((u64)sb << 32) | (u64)(u32)(NANCH - r);   // unique; idx-asc tiebreak
        }
        sk[i] = key;
    }
    __syncthreads();
    for (int kk = 2; kk <= SEGP; kk <<= 1) {
        for (int j = kk >> 1; j > 0; j >>= 1) {
            for (int i = tid; i < SEGP; i += 1024) {
                int ij = i ^ j;
                if (ij > i) {
                    u64 va = sk[i], vb = sk[ij];
                    bool up = ((i & kk) == 0);
                    if (up ? (va < vb) : (va > vb)) { sk[i] = vb; sk[ij] = va; }
                }
            }
            __syncthreads();
        }
    }
    u64* dst = runs + (size_t)blk * SEGP;
    for (int i = tid; i < SEGP; i += 1024) dst[i] = sk[i];
}

// ---------------- merge-path pairwise merge (descending, unique keys) ----------------
__device__ inline int mp_search(const u64* __restrict__ A, const u64* __restrict__ B,
                                int LA, int LB, int d) {
    int lo = max(0, d - LB), hi = min(d, LA);
    while (lo < hi) {
        int mid = (lo + hi) >> 1;
        if (A[mid] > B[d - 1 - mid]) lo = mid + 1; else hi = mid;
    }
    return lo;
}

__global__ __launch_bounds__(1024) void k_merge(
    const u64* __restrict__ in, u64* __restrict__ outk,
    int runLen, int pairsPerBatch, int outLen)
{
    int blk = blockIdx.x;
    int b = blk / pairsPerBatch, m = blk - b * pairsPerBatch;
    const u64* A = in + ((size_t)b * pairsPerBatch * 2 + 2 * m) * runLen;
    const u64* B = A + runLen;
    u64* C = outk + ((size_t)b * pairsPerBatch + m) * outLen;
    int E = (outLen + 1023) >> 10;
    int d0 = threadIdx.x * E;
    if (d0 >= outLen) return;
    int cnt = min(E, outLen - d0);
    int i = mp_search(A, B, runLen, runLen, d0);
    int j = d0 - i;
    for (int e = 0; e < cnt; ++e) {
        u64 va = (i < runLen) ? A[i] : 0ull;
        u64 vb = (j < runLen) ? B[j] : 0ull;
        bool takeA = (j >= runLen) || ((i < runLen) && (va > vb));
        C[d0 + e] = takeA ? va : vb;
        if (takeA) ++i; else ++j;
    }
}

// ---------------- final merge + emit boxes (top-6000, sorted) ----------------
__global__ __launch_bounds__(1024) void k_merge_emit(
    const u64* __restrict__ in, const float* __restrict__ out_ro,
    float* __restrict__ topBoxes, u32* __restrict__ topValid,
    const int* __restrict__ imh_p, const int* __restrict__ imw_p)
{
    int b = blockIdx.x;
    const u64* A = in + (size_t)b * 2 * RUN;
    const u64* B = A + RUN;
    float ih = (float)imh_p[0], iw = (float)imw_p[0];
    int E = (PRE + 1023) >> 10;   // 6
    int d0 = threadIdx.x * E;
    if (d0 >= PRE) return;
    int cnt = min(E, PRE - d0);
    int i = mp_search(A, B, RUN, RUN, d0);
    int j = d0 - i;
    for (int e = 0; e < cnt; ++e) {
        u64 va = (i < RUN) ? A[i] : 0ull;
        u64 vb = (j < RUN) ? B[j] : 0ull;
        bool takeA = (j >= RUN) || ((i < RUN) && (va > vb));
        u64 key = takeA ? va : vb;
        if (takeA) ++i; else ++j;
        int d = d0 + e;
        bool valid = (key >> 63) != 0ull;
        int idx = valid ? (NANCH - (int)(key & 0xFFFFFFFFull)) : 0;
        bool ok;
        float4 an = anchor_of(idx);
        float4 bx = decode_box(out_ro + (size_t)OFF_LOCS + ((size_t)b * NANCH + idx) * 4,
                               an, ih, iw, &ok);
        ((float4*)topBoxes)[(size_t)b * PRE + d] = bx;
        topValid[(size_t)b * PRE + d] = valid ? 1u : 0u;
    }
}

// ---------------- Kernel 4: lazy/JIT greedy NMS, early stop at 300 kept ----------------
__global__ __launch_bounds__(1024) void k_nms(const float* __restrict__ topBoxes,
                                              const u32* __restrict__ topValid,
                                              float* __restrict__ out)
{
    __shared__ float4 chunkB[64];
    __shared__ float4 keptB[POST];
    __shared__ u32 sup[NW32];
    __shared__ int s_nk;
    __shared__ int s_stop;
    int b = blockIdx.x, tid = threadIdx.x;
    int wave = tid >> 6, lane = tid & 63;
    const float4* tb = (const float4*)topBoxes + (size_t)b * PRE;

    for (int i = tid; i < NW32; i += 1024) sup[i] = 0u;
    if (tid == 0) { s_nk = 0; s_stop = 0; }
    __syncthreads();
    for (int r = tid; r < PRE; r += 1024)
        if (!topValid[(size_t)b * PRE + r]) atomicOr(&sup[r >> 5], 1u << (r & 31));
    if (tid == 0) atomicOr(&sup[187], 0xFFFF0000u);   // bits 6000..6015 invalid
    __syncthreads();

    for (int c = 0; c < NW64; ++c) {
        int base = c * 64;
        if (tid < 64)
            chunkB[tid] = (base + tid < PRE) ? tb[base + tid]
                                             : make_float4(0.f, 0.f, 0.f, 0.f);
        // ---- JIT: suppress this chunk's rows vs kept list so far ----
        int nk0 = s_nk;
        bool s = false;
        if (nk0 > 0 && base + lane < PRE) {
            float4 bj = tb[base + lane];
            for (int t = wave; t < nk0; t += 16)
                s |= iou_f32(keptB[t], bj) > 0.7f;
        }
        u64 bal = __ballot(s);
        if (lane == 0 && bal) {
            atomicOr(&sup[2 * c], (u32)bal);
            atomicOr(&sup[2 * c + 1], (u32)(bal >> 32));
        }
        __syncthreads();
        // ---- phase A: wave 0 resolves chunk serially ----
        if (wave == 0) {
            u64 avail = ~(((u64)sup[2 * c + 1] << 32) | (u64)sup[2 * c]);
            float4 myB = chunkB[lane];
            int nkl = s_nk;
            while (avail && nkl < POST) {
                int i = __builtin_ctzll(avail);
                float4 bi = chunkB[i];
                if (lane == 0) keptB[nkl] = bi;
                nkl++;
                bool ss = iou_f32(bi, myB) > 0.7f;
                u64 bb = __ballot(ss);
                avail &= ~((1ull << i) | bb);
            }
            if (lane == 0) { s_nk = nkl; if (nkl >= POST) s_stop = 1; }
        }
        __syncthreads();
        if (s_stop) break;
    }

    __syncthreads();
    int nk = min(s_nk, POST);
    for (int r = tid; r < POST; r += 1024) {
        float4 v = make_float4(0.f, 0.f, 0.f, 0.f);
        if (r < nk) v = keptB[r];
        ((float4*)(out + OFF_ROIS))[(size_t)b * POST + r] = v;
        out[(size_t)OFF_ROIIX + (size_t)b * POST + r] = (float)b;
    }
}

// ---------------- launch ----------------
extern "C" void kernel_launch(void* const* d_in, const int* in_sizes, int n_in,
                              void* d_out, int out_size, void* d_ws, size_t ws_size,
                              hipStream_t stream) {
    const float* x  = (const float*)d_in[0];
    const int* imh  = (const int*)d_in[1];
    const int* imw  = (const int*)d_in[2];
    // d_in[3]=conv1_w, d_in[4]=conv1_b: unused by the reference
    const float* sw = (const float*)d_in[5];
    const float* sb = (const float*)d_in[6];
    const float* lw = (const float*)d_in[7];
    const float* lb = (const float*)d_in[8];
    float* out = (float*)d_out;
    char* wsb = (char*)d_ws;

    u64*   runs0    = (u64*)(wsb);                     // 16*8*4096*8  = 4,194,304 B
    u64*   runs1    = (u64*)(wsb + 4194304);           // 16*4*6016*8  = 3,080,192 B
    u64*   runs2    = (u64*)(wsb + 7274496);           // 16*2*6016*8  = 1,540,096 B
    float* topBoxes = (float*)(wsb + 8814592);         // 16*6000*16   = 1,536,000 B
    u32*   topValid = (u32*)(wsb + 10350592);          // 16*6000*4    =   384,000 B

    hipLaunchKernelGGL(k_gemm, dim3(NB * 160), dim3(64), 0, stream,
                       x, lw, lb, sw, sb, out);
    hipLaunchKernelGGL(k_sort1, dim3(NB * 8), dim3(1024), 0, stream,
                       out, out, runs0, imh, imw);
    hipLaunchKernelGGL(k_merge, dim3(NB * 4), dim3(1024), 0, stream,
                       runs0, runs1, SEGP, 4, RUN);
    hipLaunchKernelGGL(k_merge, dim3(NB * 2), dim3(1024), 0, stream,
                       runs1, runs2, RUN, 2, RUN);
    hipLaunchKernelGGL(k_merge_emit, dim3(NB), dim3(1024), 0, stream,
                       runs2, out, topBoxes, topValid, imh, imw);
    hipLaunchKernelGGL(k_nms, dim3(NB), dim3(1024), 0, stream,
                       topBoxes, topValid, out);
}